// Round 2
// baseline (1568.828 us; speedup 1.0000x reference)
//
#include <hip/hip_runtime.h>
#include <math.h>

#define NPTS   500000
#define GRIDW  64
#define NVOX   (GRIDW*GRIDW*GRIDW)   // 262144
#define C_VOXC 96
#define C_PTC  32
#define OFFD   64
#define HID    96                    // DEC_DIM/2

// ---------------------------------------------------------------------------
// Kernel A: fold W_off/b_off/b1 through W1's offset rows.
//   Wc[t][j]   = sum_d W_off[t][d] * W1[128+d][j]        (3 x 96)
//   bcomb[j]   = b1[j] + sum_d b_off[d] * W1[128+d][j]   (96)
// ---------------------------------------------------------------------------
__global__ void fold_kernel(const float* __restrict__ W_off,
                            const float* __restrict__ b_off,
                            const float* __restrict__ W1,
                            const float* __restrict__ b1,
                            float* __restrict__ Wc,
                            float* __restrict__ bcomb) {
    int j = threadIdx.x;
    if (j >= HID) return;
    float bc = b1[j];
    float w0 = 0.f, w1 = 0.f, w2 = 0.f;
    for (int d = 0; d < OFFD; ++d) {
        float w = W1[(C_PTC + C_VOXC + d) * HID + j];
        bc += b_off[d] * w;
        w0 = fmaf(W_off[0 * OFFD + d], w, w0);
        w1 = fmaf(W_off[1 * OFFD + d], w, w1);
        w2 = fmaf(W_off[2 * OFFD + d], w, w2);
    }
    Wc[0 * HID + j] = w0;
    Wc[1 * HID + j] = w1;
    Wc[2 * HID + j] = w2;
    bcomb[j] = bc;
}

// ---------------------------------------------------------------------------
// Kernel B: per-voxel pre-multiply of the voxel branch.
//   vc[v][j] = sum_c vf[c][v] * W1[32+c][j]     (262144 x 96)
// vf reads are wave-coalesced (v contiguous across lanes); W1 reads are
// wave-uniform (scalar loads through K$).
// ---------------------------------------------------------------------------
__global__ __launch_bounds__(256) void voxgemm_kernel(
        const float* __restrict__ vf,
        const float* __restrict__ W1,
        float* __restrict__ vc) {
    const int v = blockIdx.x * 256 + threadIdx.x;
    const float* __restrict__ W1v = W1 + C_PTC * HID;   // rows 32..127

    float acc[HID];
#pragma unroll
    for (int j = 0; j < HID; ++j) acc[j] = 0.f;

    for (int c = 0; c < C_VOXC; ++c) {
        float a = vf[(size_t)c * NVOX + v];
#pragma unroll
        for (int j = 0; j < HID; ++j)
            acc[j] = fmaf(a, W1v[c * HID + j], acc[j]);
    }

    float* __restrict__ dst = vc + (size_t)v * HID;
#pragma unroll
    for (int j = 0; j < HID; j += 4) {
        float4 st = make_float4(acc[j], acc[j + 1], acc[j + 2], acc[j + 3]);
        *reinterpret_cast<float4*>(&dst[j]) = st;
    }
}

// ---------------------------------------------------------------------------
// Shared per-point tail: offsets fold + point_feat FMA + gelu + 96x3.
// acc[] comes in holding (voxel contribution + bcomb).
// ---------------------------------------------------------------------------
__device__ __forceinline__ void point_tail(
        int i, float acc[HID],
        const float* __restrict__ pf,
        const float* __restrict__ po,
        const float* __restrict__ W1,
        const float* __restrict__ W2,
        const float* __restrict__ b2,
        const float* __restrict__ Wc,
        float* __restrict__ out) {
    const float o0 = po[i * 3 + 0];
    const float o1 = po[i * 3 + 1];
    const float o2 = po[i * 3 + 2];

#pragma unroll
    for (int j = 0; j < HID; ++j) {
        float a = fmaf(o2, Wc[2 * HID + j], acc[j]);
        a = fmaf(o1, Wc[1 * HID + j], a);
        acc[j] = fmaf(o0, Wc[0 * HID + j], a);
    }

    const float* __restrict__ pfr = pf + (size_t)i * C_PTC;
#pragma unroll
    for (int kk = 0; kk < C_PTC; kk += 8) {
        float4 p0 = *reinterpret_cast<const float4*>(&pfr[kk + 0]);
        float4 p1 = *reinterpret_cast<const float4*>(&pfr[kk + 4]);
        float pv[8] = {p0.x, p0.y, p0.z, p0.w, p1.x, p1.y, p1.z, p1.w};
#pragma unroll
        for (int k = 0; k < 8; ++k) {
            const float fk = pv[k];
            const float* __restrict__ wrow = W1 + (kk + k) * HID;
#pragma unroll
            for (int j = 0; j < HID; ++j)
                acc[j] = fmaf(fk, wrow[j], acc[j]);
        }
    }

    float f0 = b2[0], f1 = b2[1], f2 = b2[2];
#pragma unroll
    for (int j = 0; j < HID; ++j) {
        const float s = acc[j];
        const float h = 0.5f * s * (1.f + erff(s * 0.70710678118654752440f));
        f0 = fmaf(h, W2[j * 3 + 0], f0);
        f1 = fmaf(h, W2[j * 3 + 1], f1);
        f2 = fmaf(h, W2[j * 3 + 2], f2);
    }

    out[i * 3 + 0] = f0;
    out[i * 3 + 1] = f1;
    out[i * 3 + 2] = f2;
}

// ---------------------------------------------------------------------------
// Kernel C (fast path): per-point decoder reading pre-multiplied vc rows.
// ---------------------------------------------------------------------------
__global__ __launch_bounds__(256) void point_kernel(
        const int* __restrict__ coords,
        const float* __restrict__ pf,
        const float* __restrict__ po,
        const float* __restrict__ W1,
        const float* __restrict__ W2,
        const float* __restrict__ b2,
        const float* __restrict__ Wc,
        const float* __restrict__ bcomb,
        const float* __restrict__ vc,
        float* __restrict__ out) {
    const int i = blockIdx.x * 256 + threadIdx.x;
    if (i >= NPTS) return;

    const int x = coords[i * 3 + 0];
    const int y = coords[i * 3 + 1];
    const int z = coords[i * 3 + 2];
    const int vidx = (z * GRIDW + y) * GRIDW + x;

    float acc[HID];
    const float* __restrict__ vrow = vc + (size_t)vidx * HID;
#pragma unroll
    for (int j = 0; j < HID; j += 4) {
        float4 vv = *reinterpret_cast<const float4*>(&vrow[j]);
        acc[j + 0] = vv.x + bcomb[j + 0];
        acc[j + 1] = vv.y + bcomb[j + 1];
        acc[j + 2] = vv.z + bcomb[j + 2];
        acc[j + 3] = vv.w + bcomb[j + 3];
    }

    point_tail(i, acc, pf, po, W1, W2, b2, Wc, out);
}

// ---------------------------------------------------------------------------
// Kernel C' (fallback if ws too small): gather raw vf channels per point.
// 96 strided 4B loads/point — slow but correct, no big workspace needed.
// ---------------------------------------------------------------------------
__global__ __launch_bounds__(256) void point_direct_kernel(
        const int* __restrict__ coords,
        const float* __restrict__ vf,
        const float* __restrict__ pf,
        const float* __restrict__ po,
        const float* __restrict__ W1,
        const float* __restrict__ W2,
        const float* __restrict__ b2,
        const float* __restrict__ Wc,
        const float* __restrict__ bcomb,
        float* __restrict__ out) {
    const int i = blockIdx.x * 256 + threadIdx.x;
    if (i >= NPTS) return;

    const int x = coords[i * 3 + 0];
    const int y = coords[i * 3 + 1];
    const int z = coords[i * 3 + 2];
    const int vidx = (z * GRIDW + y) * GRIDW + x;

    float acc[HID];
#pragma unroll
    for (int j = 0; j < HID; ++j) acc[j] = bcomb[j];

    const float* __restrict__ W1v = W1 + C_PTC * HID;
    for (int c = 0; c < C_VOXC; ++c) {
        const float a = vf[(size_t)c * NVOX + vidx];
#pragma unroll
        for (int j = 0; j < HID; ++j)
            acc[j] = fmaf(a, W1v[c * HID + j], acc[j]);
    }

    point_tail(i, acc, pf, po, W1, W2, b2, Wc, out);
}

// ---------------------------------------------------------------------------
extern "C" void kernel_launch(void* const* d_in, const int* in_sizes, int n_in,
                              void* d_out, int out_size, void* d_ws, size_t ws_size,
                              hipStream_t stream) {
    const float* vf    = (const float*)d_in[0];  // (96,64,64,64)
    const int*   vcrd  = (const int*)  d_in[1];  // (500000,3)
    const float* pf    = (const float*)d_in[2];  // (500000,32)
    const float* po    = (const float*)d_in[3];  // (500000,3)
    const float* W_off = (const float*)d_in[4];  // (3,64)
    const float* b_off = (const float*)d_in[5];  // (64,)
    const float* W1    = (const float*)d_in[6];  // (192,96)
    const float* b1    = (const float*)d_in[7];  // (96,)
    const float* W2    = (const float*)d_in[8];  // (96,3)
    const float* b2    = (const float*)d_in[9];  // (3,)
    float* out = (float*)d_out;

    // workspace layout (floats): [0..287] Wc, [384..479] bcomb, [1024..] vc
    float* Wc    = (float*)d_ws;
    float* bcomb = Wc + 384;
    float* vcb   = Wc + 1024;   // NVOX*96 floats = 96 MiB

    const size_t need = (size_t)(1024 + (size_t)NVOX * HID) * sizeof(float);

    fold_kernel<<<1, 128, 0, stream>>>(W_off, b_off, W1, b1, Wc, bcomb);

    if (ws_size >= need) {
        voxgemm_kernel<<<NVOX / 256, 256, 0, stream>>>(vf, W1, vcb);
        point_kernel<<<(NPTS + 255) / 256, 256, 0, stream>>>(
            vcrd, pf, po, W1, W2, b2, Wc, bcomb, vcb, out);
    } else {
        point_direct_kernel<<<(NPTS + 255) / 256, 256, 0, stream>>>(
            vcrd, vf, pf, po, W1, W2, b2, Wc, bcomb, out);
    }
}

// Round 3
// 376.626 us; speedup vs baseline: 4.1655x; 4.1655x over previous
//
#include <hip/hip_runtime.h>
#include <math.h>

#define NPTS   500000
#define GRIDW  64
#define NVOX   (GRIDW*GRIDW*GRIDW)   // 262144
#define C_VOXC 96
#define C_PTC  32
#define OFFD   64
#define HID    96                    // DEC_DIM/2
#define HHALF  48

// ---------------------------------------------------------------------------
// Branch-free exact-GELU via Abramowitz-Stegun 7.1.26 erf (abs err 1.5e-7).
// ~16 VALU ops, no divergence, no libcall.
// ---------------------------------------------------------------------------
__device__ __forceinline__ float gelu_fast(float s) {
    const float u  = s * 0.70710678118654752440f;
    const float au = fabsf(u);
    const float t  = __fdividef(1.0f, fmaf(0.3275911f, au, 1.0f));
    float p = fmaf(1.061405429f, t, -1.453152027f);
    p = fmaf(p, t, 1.421413741f);
    p = fmaf(p, t, -0.284496736f);
    p = fmaf(p, t, 0.254829592f);
    p *= t;
    const float e = __expf(-u * u);
    float r = fmaf(-p, e, 1.0f);        // erf(|u|)
    r = copysignf(r, u);                // erf(u)
    return 0.5f * s * (1.0f + r);
}

// ---------------------------------------------------------------------------
// Kernel A: fold W_off/b_off/b1 through W1's offset rows.
// ---------------------------------------------------------------------------
__global__ void fold_kernel(const float* __restrict__ W_off,
                            const float* __restrict__ b_off,
                            const float* __restrict__ W1,
                            const float* __restrict__ b1,
                            float* __restrict__ Wc,
                            float* __restrict__ bcomb) {
    int j = threadIdx.x;
    if (j >= HID) return;
    float bc = b1[j];
    float w0 = 0.f, w1 = 0.f, w2 = 0.f;
    for (int d = 0; d < OFFD; ++d) {
        float w = W1[(C_PTC + C_VOXC + d) * HID + j];
        bc += b_off[d] * w;
        w0 = fmaf(W_off[0 * OFFD + d], w, w0);
        w1 = fmaf(W_off[1 * OFFD + d], w, w1);
        w2 = fmaf(W_off[2 * OFFD + d], w, w2);
    }
    Wc[0 * HID + j] = w0;
    Wc[1 * HID + j] = w1;
    Wc[2 * HID + j] = w2;
    bcomb[j] = bc;
}

// ---------------------------------------------------------------------------
// Kernel B: per-voxel pre-multiply (unchanged — control group; ran <=235us).
// ---------------------------------------------------------------------------
__global__ __launch_bounds__(256) void voxgemm_kernel(
        const float* __restrict__ vf,
        const float* __restrict__ W1,
        float* __restrict__ vc) {
    const int v = blockIdx.x * 256 + threadIdx.x;
    const float* __restrict__ W1v = W1 + C_PTC * HID;

    float acc[HID];
#pragma unroll
    for (int j = 0; j < HID; ++j) acc[j] = 0.f;

    for (int c = 0; c < C_VOXC; ++c) {
        float a = vf[(size_t)c * NVOX + v];
#pragma unroll
        for (int j = 0; j < HID; ++j)
            acc[j] = fmaf(a, W1v[c * HID + j], acc[j]);
    }

    float* __restrict__ dst = vc + (size_t)v * HID;
#pragma unroll
    for (int j = 0; j < HID; j += 4) {
        float4 st = make_float4(acc[j], acc[j + 1], acc[j + 2], acc[j + 3]);
        *reinterpret_cast<float4*>(&dst[j]) = st;
    }
}

// ---------------------------------------------------------------------------
// Kernel C v2: per-point decoder.
//  - gather de-serialized: vrow loads issue early, are ADDED late (acc no
//    longer initialized from them, so the FMA stream doesn't wait on L3)
//  - j split into two halves of 48 to cap live VGPRs (~145 peak, 3 waves/SIMD)
//  - gelu_fast instead of erff libcall
// ---------------------------------------------------------------------------
__global__ __launch_bounds__(256) void point_kernel(
        const int* __restrict__ coords,
        const float* __restrict__ pf,
        const float* __restrict__ po,
        const float* __restrict__ W1,
        const float* __restrict__ W2,
        const float* __restrict__ b2,
        const float* __restrict__ Wc,
        const float* __restrict__ bcomb,
        const float* __restrict__ vc,
        float* __restrict__ out) {
    const int i = blockIdx.x * 256 + threadIdx.x;
    if (i >= NPTS) return;

    const int x = coords[i * 3 + 0];
    const int y = coords[i * 3 + 1];
    const int z = coords[i * 3 + 2];
    const int vidx = (z * GRIDW + y) * GRIDW + x;
    const float4* __restrict__ vrow4 =
        reinterpret_cast<const float4*>(vc + (size_t)vidx * HID);

    // issue first-half gather immediately (consumed ~1700 instrs later)
    float4 vrA[12];
#pragma unroll
    for (int q = 0; q < 12; ++q) vrA[q] = vrow4[q];

    const float o0 = po[i * 3 + 0];
    const float o1 = po[i * 3 + 1];
    const float o2 = po[i * 3 + 2];

    float pfr[C_PTC];
    {
        const float4* __restrict__ p4 =
            reinterpret_cast<const float4*>(pf + (size_t)i * C_PTC);
#pragma unroll
        for (int q = 0; q < 8; ++q) {
            float4 v = p4[q];
            pfr[4 * q + 0] = v.x; pfr[4 * q + 1] = v.y;
            pfr[4 * q + 2] = v.z; pfr[4 * q + 3] = v.w;
        }
    }

    float f0 = b2[0], f1 = b2[1], f2 = b2[2];
    float4 vrB[12];

#pragma unroll
    for (int h = 0; h < 2; ++h) {
        const int j0 = h * HHALF;
        float acc[HHALF];

        // init from folded bias + offset projection (independent of gather)
#pragma unroll
        for (int j = 0; j < HHALF; ++j) {
            float a = fmaf(o2, Wc[2 * HID + j0 + j], bcomb[j0 + j]);
            a = fmaf(o1, Wc[1 * HID + j0 + j], a);
            acc[j] = fmaf(o0, Wc[0 * HID + j0 + j], a);
        }

        // point_feat x W1 half-column (uniform weight loads)
#pragma unroll
        for (int k = 0; k < C_PTC; ++k) {
            const float fk = pfr[k];
            const float* __restrict__ wrow = W1 + k * HID + j0;
#pragma unroll
            for (int j = 0; j < HHALF; ++j)
                acc[j] = fmaf(fk, wrow[j], acc[j]);
        }

        // fold in the gathered voxel half; prefetch the second half
        if (h == 0) {
#pragma unroll
            for (int q = 0; q < 12; ++q) {
                acc[4 * q + 0] += vrA[q].x;
                acc[4 * q + 1] += vrA[q].y;
                acc[4 * q + 2] += vrA[q].z;
                acc[4 * q + 3] += vrA[q].w;
            }
#pragma unroll
            for (int q = 0; q < 12; ++q) vrB[q] = vrow4[12 + q];
        } else {
#pragma unroll
            for (int q = 0; q < 12; ++q) {
                acc[4 * q + 0] += vrB[q].x;
                acc[4 * q + 1] += vrB[q].y;
                acc[4 * q + 2] += vrB[q].z;
                acc[4 * q + 3] += vrB[q].w;
            }
        }

        // gelu + final 48x3 partial
#pragma unroll
        for (int j = 0; j < HHALF; ++j) {
            const float hh = gelu_fast(acc[j]);
            f0 = fmaf(hh, W2[(j0 + j) * 3 + 0], f0);
            f1 = fmaf(hh, W2[(j0 + j) * 3 + 1], f1);
            f2 = fmaf(hh, W2[(j0 + j) * 3 + 2], f2);
        }
    }

    out[i * 3 + 0] = f0;
    out[i * 3 + 1] = f1;
    out[i * 3 + 2] = f2;
}

// ---------------------------------------------------------------------------
// Fallback (ws too small — proven unused, kept for safety): direct gather.
// ---------------------------------------------------------------------------
__global__ __launch_bounds__(256) void point_direct_kernel(
        const int* __restrict__ coords,
        const float* __restrict__ vf,
        const float* __restrict__ pf,
        const float* __restrict__ po,
        const float* __restrict__ W1,
        const float* __restrict__ W2,
        const float* __restrict__ b2,
        const float* __restrict__ Wc,
        const float* __restrict__ bcomb,
        float* __restrict__ out) {
    const int i = blockIdx.x * 256 + threadIdx.x;
    if (i >= NPTS) return;

    const int x = coords[i * 3 + 0];
    const int y = coords[i * 3 + 1];
    const int z = coords[i * 3 + 2];
    const int vidx = (z * GRIDW + y) * GRIDW + x;

    float acc[HID];
#pragma unroll
    for (int j = 0; j < HID; ++j) acc[j] = bcomb[j];

    const float* __restrict__ W1v = W1 + C_PTC * HID;
    for (int c = 0; c < C_VOXC; ++c) {
        const float a = vf[(size_t)c * NVOX + vidx];
#pragma unroll
        for (int j = 0; j < HID; ++j)
            acc[j] = fmaf(a, W1v[c * HID + j], acc[j]);
    }

    const float o0 = po[i * 3 + 0];
    const float o1 = po[i * 3 + 1];
    const float o2 = po[i * 3 + 2];
#pragma unroll
    for (int j = 0; j < HID; ++j) {
        float a = fmaf(o2, Wc[2 * HID + j], acc[j]);
        a = fmaf(o1, Wc[1 * HID + j], a);
        acc[j] = fmaf(o0, Wc[0 * HID + j], a);
    }

    const float* __restrict__ pfr = pf + (size_t)i * C_PTC;
    for (int k = 0; k < C_PTC; ++k) {
        const float fk = pfr[k];
#pragma unroll
        for (int j = 0; j < HID; ++j)
            acc[j] = fmaf(fk, W1[k * HID + j], acc[j]);
    }

    float f0 = b2[0], f1 = b2[1], f2 = b2[2];
#pragma unroll
    for (int j = 0; j < HID; ++j) {
        const float hh = gelu_fast(acc[j]);
        f0 = fmaf(hh, W2[j * 3 + 0], f0);
        f1 = fmaf(hh, W2[j * 3 + 1], f1);
        f2 = fmaf(hh, W2[j * 3 + 2], f2);
    }

    out[i * 3 + 0] = f0;
    out[i * 3 + 1] = f1;
    out[i * 3 + 2] = f2;
}

// ---------------------------------------------------------------------------
extern "C" void kernel_launch(void* const* d_in, const int* in_sizes, int n_in,
                              void* d_out, int out_size, void* d_ws, size_t ws_size,
                              hipStream_t stream) {
    const float* vf    = (const float*)d_in[0];
    const int*   vcrd  = (const int*)  d_in[1];
    const float* pf    = (const float*)d_in[2];
    const float* po    = (const float*)d_in[3];
    const float* W_off = (const float*)d_in[4];
    const float* b_off = (const float*)d_in[5];
    const float* W1    = (const float*)d_in[6];
    const float* b1    = (const float*)d_in[7];
    const float* W2    = (const float*)d_in[8];
    const float* b2    = (const float*)d_in[9];
    float* out = (float*)d_out;

    float* Wc    = (float*)d_ws;
    float* bcomb = Wc + 384;
    float* vcb   = Wc + 1024;   // NVOX*96 floats = 96 MiB

    const size_t need = (size_t)(1024 + (size_t)NVOX * HID) * sizeof(float);

    fold_kernel<<<1, 128, 0, stream>>>(W_off, b_off, W1, b1, Wc, bcomb);

    if (ws_size >= need) {
        voxgemm_kernel<<<NVOX / 256, 256, 0, stream>>>(vf, W1, vcb);
        point_kernel<<<(NPTS + 255) / 256, 256, 0, stream>>>(
            vcrd, pf, po, W1, W2, b2, Wc, bcomb, vcb, out);
    } else {
        point_direct_kernel<<<(NPTS + 255) / 256, 256, 0, stream>>>(
            vcrd, vf, pf, po, W1, W2, b2, Wc, bcomb, out);
    }
}